// Round 7
// baseline (274.849 us; speedup 1.0000x reference)
//
#include <hip/hip_runtime.h>
#include <hip/hip_bf16.h>

#define HID 128
#define LDK 136    // LDS row stride in shorts (272B): +4-bank skew/row, additive offsets
#define CPB 4      // cells per edge-block
#define CAP 16     // edges per cell (E/G)

// wt regions (bf16 elements): Wt[n][k] transposed weights
#define WT_E2 0        // [128][128]
#define WT_M1 16384    // [128][256]
#define WT_M2 49152    // [128][128]
#define WT_U1 65536    // [128][128]
#define WT_U2 81920    // [128][128]
#define WT_TOTAL 98304

typedef __attribute__((ext_vector_type(8))) short bf16x8;
typedef __attribute__((ext_vector_type(4))) float f32x4;

#define MFMA(a, b, c) __builtin_amdgcn_mfma_f32_16x16x32_bf16(a, b, c, 0, 0, 0)

__device__ __forceinline__ float silu_f(float x) {
    return x * (1.0f / (1.0f + __expf(-x)));
}

__device__ __forceinline__ short f2b(float x) {
    __hip_bfloat16 h = __float2bfloat16(x);   // RNE
    return *(short*)&h;
}

__device__ __forceinline__ float b2f(unsigned short u) {
    union { unsigned u32; float f; } v;
    v.u32 = ((unsigned)u) << 16;
    return v.f;
}

__device__ __forceinline__ void zero_acc(f32x4 acc[4][2]) {
    #pragma unroll
    for (int m = 0; m < 4; ++m) {
        acc[m][0] = (f32x4)(0.0f);
        acc[m][1] = (f32x4)(0.0f);
    }
}

// Fully-unrolled K=128 GEMM over 4 A-row-tiles (rows e4*16+q) x 32 weight cols.
// NOTE (in-place discipline): reads the ENTIRE act buffer into acc; caller
// must __syncthreads() between this and any write to the same buffer.
template<int LDB, bool SWAP>
__device__ __forceinline__ void gemm128(f32x4 acc[4][2], const short* actb,
                                        const short* __restrict__ w0)
{
    const short* __restrict__ w1 = w0 + 16 * LDB;
    #pragma unroll
    for (int ks = 0; ks < 4; ++ks) {
        bf16x8 wa = *(const bf16x8*)(w0 + ks * 32);
        bf16x8 wb = *(const bf16x8*)(w1 + ks * 32);
        #pragma unroll
        for (int e4 = 0; e4 < 4; ++e4) {
            bf16x8 a = *(const bf16x8*)(actb + e4 * (16 * LDK) + ks * 32);
            if (SWAP) {   // weights as A: C rows = features, cols = edges
                acc[e4][0] = MFMA(wa, a, acc[e4][0]);
                acc[e4][1] = MFMA(wb, a, acc[e4][1]);
            } else {      // act as A: C rows = edges, cols = features
                acc[e4][0] = MFMA(a, wa, acc[e4][0]);
                acc[e4][1] = MFMA(a, wb, acc[e4][1]);
            }
        }
    }
}

// swapped-orientation epilogue: lane holds 4 consecutive feats of one edge.
__device__ __forceinline__ void epi_swap(f32x4 acc[4][2], const float* __restrict__ bias_f,
                                         short* wbase, bool act)
{
    #pragma unroll
    for (int nf = 0; nf < 2; ++nf) {
        float4 bb = *(const float4*)(bias_f + nf * 16);
        #pragma unroll
        for (int e4 = 0; e4 < 4; ++e4) {
            f32x4 v = acc[e4][nf];
            float z0 = v[0] + bb.x, z1 = v[1] + bb.y;
            float z2 = v[2] + bb.z, z3 = v[3] + bb.w;
            if (act) { z0 = silu_f(z0); z1 = silu_f(z1); z2 = silu_f(z2); z3 = silu_f(z3); }
            short4 s4;
            s4.x = f2b(z0); s4.y = f2b(z1); s4.z = f2b(z2); s4.w = f2b(z3);
            *(short4*)(wbase + e4 * (16 * LDK) + nf * 16) = s4;
        }
    }
}

// ---------------------------------------------------------------------------
// prep0: edge binning (stores SOURCE NODE ID per slot) + weight conversion
// ---------------------------------------------------------------------------
extern "C" __global__ void __launch_bounds__(256)
prep0(const int* __restrict__ ei, int* __restrict__ cnt, int* __restrict__ bin, int E,
      const float* __restrict__ ew2, const float* __restrict__ mw1,
      const float* __restrict__ mw2, const float* __restrict__ uw1,
      const float* __restrict__ uw2, short* __restrict__ wt)
{
    int nbin = (E + 255) / 256;
    if ((int)blockIdx.x < nbin) {
        int e = blockIdx.x * 256 + threadIdx.x;
        if (e < E) {
            int j = ei[E + e];
            int i = ei[e];
            int slot = atomicAdd(&cnt[j], 1);
            if (slot < CAP) bin[(size_t)j * CAP + slot] = i;
        }
        return;
    }
    int idx = (blockIdx.x - nbin) * 256 + threadIdx.x;
    if (idx >= WT_TOTAL) return;
    int r = idx;
    if (r < 16384) { int n = r >> 7, k = r & 127; wt[idx] = f2b(ew2[k * HID + n]); return; }
    r -= 16384;
    if (r < 32768) { int n = r >> 8, k = r & 255; wt[idx] = f2b(mw1[k * HID + n]); return; }
    r -= 32768;
    if (r < 16384) { int n = r >> 7, k = r & 127; wt[idx] = f2b(mw2[k * HID + n]); return; }
    r -= 16384;
    if (r < 16384) { int n = r >> 7, k = r & 127; wt[idx] = f2b(uw1[k * HID + n]); return; }
    r -= 16384;
    { int n = r >> 7, k = r & 127; wt[idx] = f2b(uw2[k * HID + n]); return; }
}

// ---------------------------------------------------------------------------
// prep_gemm: pre[node] = emb[node] @ mw1[:128] + mb1   (bf16 out)
// ---------------------------------------------------------------------------
extern "C" __global__ void __launch_bounds__(256, 4)
prep_gemm(const float* __restrict__ emb, const float* __restrict__ mb1,
          const short* __restrict__ wt, unsigned short* __restrict__ pre)
{
    __shared__ short s_x[64 * LDK];
    const int t  = threadIdx.x;
    const int r0 = blockIdx.x * 64;

    {   // stage 64 fp32 rows -> bf16 LDS (padded rows)
        int row = t >> 2, part = t & 3;
        const float4* src = (const float4*)(emb + (size_t)(r0 + row) * HID + part * 32);
        short* dst = s_x + row * LDK + part * 32;
        #pragma unroll
        for (int c = 0; c < 4; ++c) {
            float4 v0 = src[c * 2], v1 = src[c * 2 + 1];
            short4 a4, b4;
            a4.x = f2b(v0.x); a4.y = f2b(v0.y); a4.z = f2b(v0.z); a4.w = f2b(v0.w);
            b4.x = f2b(v1.x); b4.y = f2b(v1.y); b4.z = f2b(v1.z); b4.w = f2b(v1.w);
            *(short4*)(dst + c * 8)     = a4;
            *(short4*)(dst + c * 8 + 4) = b4;
        }
    }
    __syncthreads();

    const int lane = t & 63, q = lane & 15, h = lane >> 4, nb = (t >> 6) * 32;
    f32x4 acc[4][2];
    zero_acc(acc);
    gemm128<256, false>(acc, s_x + q * LDK + h * 8, wt + WT_M1 + (nb + q) * 256 + h * 8);

    #pragma unroll
    for (int nf = 0; nf < 2; ++nf) {
        int n = nb + nf * 16 + q;
        float bb = mb1[n];
        #pragma unroll
        for (int m = 0; m < 4; ++m)
            #pragma unroll
            for (int r = 0; r < 4; ++r)
                pre[(size_t)(r0 + m * 16 + h * 4 + r) * HID + n] =
                    (unsigned short)f2b(acc[m][nf][r] + bb);
    }
}

// ---------------------------------------------------------------------------
// edge kernel: 4 cells x 16 binned edges. SINGLE in-place act buffer
// (GEMM reads all rows -> barrier -> epi writes), 21.8 KB LDS -> 7 blocks/CU.
// ---------------------------------------------------------------------------
extern "C" __global__ void __launch_bounds__(256, 7)
edge_kernel(const float* __restrict__ npos,
            const float* __restrict__ gpos,
            const float* __restrict__ ew1, const float* __restrict__ eb1,
            const float* __restrict__ eb2, const float* __restrict__ mb2,
            const float* __restrict__ ub1, const float* __restrict__ ub2,
            const short* __restrict__ wt,
            const int* __restrict__ cnt,
            const int* __restrict__ bin,
            const unsigned short* __restrict__ pre,
            float* __restrict__ out)
{
    __shared__ short s[64 * LDK];        // in-place act buffer (all layers)
    __shared__ short s_mean[16 * LDK];   // mean rows 0..3 real, 4..15 zero

    const int t  = threadIdx.x;
    const int c0 = blockIdx.x * CPB;
    const int lane = t & 63, q = lane & 15, h = lane >> 4, nb = (t >> 6) * 32;

    const short* rs = s + q * LDK + h * 8;        // GEMM read base (rows e4*16+q)
    short* ws = s + q * LDK + nb + h * 4;         // epi write base

    // ---- gather: node ids for this thread's 4 edge rows (e4*16+q)
    int idx[4];
    #pragma unroll
    for (int e4 = 0; e4 < 4; ++e4)
        idx[e4] = bin[c0 * CAP + e4 * 16 + q];

    float np0[4], np1[4], np2[4];
    #pragma unroll
    for (int e4 = 0; e4 < 4; ++e4) {
        const float* p = npos + (size_t)idx[e4] * 3;
        np0[e4] = p[0]; np1[e4] = p[1]; np2[e4] = p[2];
    }

    // wave-uniform: grid positions + counts (SGPR loads)
    float g0[4], g1[4], g2[4], inv[4];
    #pragma unroll
    for (int m = 0; m < 4; ++m) {
        const float* gp = gpos + (size_t)(c0 + m) * 3;
        g0[m] = gp[0]; g1[m] = gp[1]; g2[m] = gp[2];
        int c = cnt[c0 + m];
        inv[m] = 1.0f / (float)(c > 0 ? c : 1);
    }

    const int f00 = nb + h * 4;

    // ---- L1 (direct fp32): h1 = silu(np . ew1[0:3] + gp . ew1[3:6] + eb1) -> s
    #pragma unroll
    for (int nf = 0; nf < 2; ++nf) {
        int f0 = f00 + nf * 16;
        float4 wn0 = *(const float4*)(ew1 + 0 * HID + f0);
        float4 wn1 = *(const float4*)(ew1 + 1 * HID + f0);
        float4 wn2 = *(const float4*)(ew1 + 2 * HID + f0);
        float4 wg0 = *(const float4*)(ew1 + 3 * HID + f0);
        float4 wg1 = *(const float4*)(ew1 + 4 * HID + f0);
        float4 wg2 = *(const float4*)(ew1 + 5 * HID + f0);
        float4 bb  = *(const float4*)(eb1 + f0);
        #pragma unroll
        for (int e4 = 0; e4 < 4; ++e4) {
            float bx = bb.x + g0[e4] * wg0.x + g1[e4] * wg1.x + g2[e4] * wg2.x;
            float by = bb.y + g0[e4] * wg0.y + g1[e4] * wg1.y + g2[e4] * wg2.y;
            float bz = bb.z + g0[e4] * wg0.z + g1[e4] * wg1.z + g2[e4] * wg2.z;
            float bw = bb.w + g0[e4] * wg0.w + g1[e4] * wg1.w + g2[e4] * wg2.w;
            float z0 = silu_f(bx + np0[e4] * wn0.x + np1[e4] * wn1.x + np2[e4] * wn2.x);
            float z1 = silu_f(by + np0[e4] * wn0.y + np1[e4] * wn1.y + np2[e4] * wn2.y);
            float z2 = silu_f(bz + np0[e4] * wn0.z + np1[e4] * wn1.z + np2[e4] * wn2.z);
            float z3 = silu_f(bw + np0[e4] * wn0.w + np1[e4] * wn1.w + np2[e4] * wn2.w);
            short4 s4;
            s4.x = f2b(z0); s4.y = f2b(z1); s4.z = f2b(z2); s4.w = f2b(z3);
            *(short4*)(ws + e4 * (16 * LDK) + nf * 16) = s4;
        }
    }

    // T14: issue pre[] gather now; consumed after L3's GEMM
    uint2 pg[4][2];
    #pragma unroll
    for (int e4 = 0; e4 < 4; ++e4) {
        const unsigned short* prow = pre + (size_t)idx[e4] * HID;
        pg[e4][0] = *(const uint2*)(prow + nb + h * 4);
        pg[e4][1] = *(const uint2*)(prow + nb + 16 + h * 4);
    }
    __syncthreads();                                   // B1: h1 visible

    f32x4 acc[4][2];

    // ---- L2: pos = h1 @ ew2 + eb2   (swapped, in-place)
    zero_acc(acc);
    gemm128<128, true>(acc, rs, wt + WT_E2 + (nb + q) * 128 + h * 8);
    __syncthreads();                                   // B2: all reads of h1 done
    epi_swap(acc, eb2 + f00, ws, false);
    __syncthreads();                                   // B3: pos visible

    // ---- L3: h2 = silu(pos @ mw1[128:] + pre[i])   (swapped, in-place)
    zero_acc(acc);
    gemm128<256, true>(acc, rs, wt + WT_M1 + (nb + q) * 256 + 128 + h * 8);
    __syncthreads();                                   // B4: all reads of pos done
    #pragma unroll
    for (int e4 = 0; e4 < 4; ++e4) {
        #pragma unroll
        for (int nf = 0; nf < 2; ++nf) {
            uint2 g = pg[e4][nf];
            f32x4 v = acc[e4][nf];
            float z0 = silu_f(v[0] + b2f((unsigned short)(g.x & 0xffff)));
            float z1 = silu_f(v[1] + b2f((unsigned short)(g.x >> 16)));
            float z2 = silu_f(v[2] + b2f((unsigned short)(g.y & 0xffff)));
            float z3 = silu_f(v[3] + b2f((unsigned short)(g.y >> 16)));
            short4 s4;
            s4.x = f2b(z0); s4.y = f2b(z1); s4.z = f2b(z2); s4.w = f2b(z3);
            *(short4*)(ws + e4 * (16 * LDK) + nf * 16) = s4;
        }
    }
    __syncthreads();                                   // B5: h2 visible

    // ---- L4: message = h2 @ mw2 (act-as-A); per-cell mean -> s_mean
    zero_acc(acc);
    gemm128<128, false>(acc, rs, wt + WT_M2 + (nb + q) * 128 + h * 8);

    #pragma unroll
    for (int m = 0; m < 4; ++m) {
        #pragma unroll
        for (int nf = 0; nf < 2; ++nf) {
            f32x4 v = acc[m][nf];
            float ssum = (v[0] + v[1]) + (v[2] + v[3]);
            ssum += __shfl_xor(ssum, 16);
            ssum += __shfl_xor(ssum, 32);
            if (h == 0) {
                int n = nb + nf * 16 + q;
                s_mean[m * LDK + n] = f2b(ssum * inv[m] + mb2[n]);
            }
        }
    }
    for (int z = t; z < 12 * LDK; z += 256) s_mean[4 * LDK + z] = 0;
    __syncthreads();                                   // B6: mean visible (+L4 reads done)

    // ---- u1: silu(mean @ uw1 + ub1) -> s rows 16..31
    f32x4 a2[2];
    a2[0] = (f32x4)(0.0f); a2[1] = (f32x4)(0.0f);
    {
        const short* w0 = wt + WT_U1 + (nb + q) * 128 + h * 8;
        const short* w1 = w0 + 16 * 128;
        const short* ab = s_mean + q * LDK + h * 8;
        #pragma unroll
        for (int ks = 0; ks < 4; ++ks) {
            bf16x8 a  = *(const bf16x8*)(ab + ks * 32);
            bf16x8 b0 = *(const bf16x8*)(w0 + ks * 32);
            bf16x8 b1 = *(const bf16x8*)(w1 + ks * 32);
            a2[0] = MFMA(a, b0, a2[0]);
            a2[1] = MFMA(a, b1, a2[1]);
        }
    }
    #pragma unroll
    for (int nf = 0; nf < 2; ++nf) {
        int n = nb + nf * 16 + q;
        float bb = ub1[n];
        #pragma unroll
        for (int r = 0; r < 4; ++r)
            s[(16 + h * 4 + r) * LDK + n] = f2b(silu_f(a2[nf][r] + bb));
    }
    __syncthreads();                                   // B7: u1 visible

    // ---- u2: out = h @ uw2 + ub2  (C rows 0..3 = cells)
    a2[0] = (f32x4)(0.0f); a2[1] = (f32x4)(0.0f);
    {
        const short* w0 = wt + WT_U2 + (nb + q) * 128 + h * 8;
        const short* w1 = w0 + 16 * 128;
        const short* ab = s + (16 + q) * LDK + h * 8;
        #pragma unroll
        for (int ks = 0; ks < 4; ++ks) {
            bf16x8 a  = *(const bf16x8*)(ab + ks * 32);
            bf16x8 b0 = *(const bf16x8*)(w0 + ks * 32);
            bf16x8 b1 = *(const bf16x8*)(w1 + ks * 32);
            a2[0] = MFMA(a, b0, a2[0]);
            a2[1] = MFMA(a, b1, a2[1]);
        }
    }
    if (h == 0) {
        #pragma unroll
        for (int nf = 0; nf < 2; ++nf) {
            int n = nb + nf * 16 + q;
            float bb = ub2[n];
            #pragma unroll
            for (int r = 0; r < 4; ++r)
                out[(size_t)(c0 + r) * HID + n] = a2[nf][r] + bb;
        }
    }
}

// ---------------------------------------------------------------------------
extern "C" void kernel_launch(void* const* d_in, const int* in_sizes, int n_in,
                              void* d_out, int out_size, void* d_ws, size_t ws_size,
                              hipStream_t stream)
{
    const float* emb  = (const float*)d_in[0];
    const float* npos = (const float*)d_in[1];
    const float* gpos = (const float*)d_in[2];
    const int*   ei   = (const int*)d_in[3];
    const float* ew1  = (const float*)d_in[4];
    const float* eb1  = (const float*)d_in[5];
    const float* ew2  = (const float*)d_in[6];
    const float* eb2  = (const float*)d_in[7];
    const float* mw1  = (const float*)d_in[8];
    const float* mb1  = (const float*)d_in[9];
    const float* mw2  = (const float*)d_in[10];
    const float* mb2  = (const float*)d_in[11];
    const float* uw1  = (const float*)d_in[12];
    const float* ub1  = (const float*)d_in[13];
    const float* uw2  = (const float*)d_in[14];
    const float* ub2  = (const float*)d_in[15];

    const int E  = in_sizes[3] / 2;
    const int G  = in_sizes[2] / 3;
    const int NN = in_sizes[0] / HID;

    // ws layout: pre bf16[NN*HID] | cnt int[G] | bin int[G*CAP] | wt bf16[WT_TOTAL]
    unsigned short* pre = (unsigned short*)d_ws;
    char* p = (char*)d_ws + (size_t)NN * HID * 2;
    int*   cnt = (int*)p;                 p += (size_t)G * 4;
    int*   bin = (int*)p;                 p += (size_t)G * CAP * 4;
    short* wt  = (short*)p;

    hipMemsetAsync(cnt, 0, (size_t)G * (4 + CAP * 4), stream);   // cnt + bin

    int nbin = (E + 255) / 256;
    int ncvt = (WT_TOTAL + 255) / 256;
    prep0<<<nbin + ncvt, 256, 0, stream>>>(ei, cnt, bin, E, ew2, mw1, mw2, uw1, uw2, wt);
    prep_gemm<<<NN / 64, 256, 0, stream>>>(emb, mb1, wt, pre);
    edge_kernel<<<G / CPB, 256, 0, stream>>>(npos, gpos, ew1, eb1, eb2, mb2, ub1, ub2,
                                             wt, cnt, bin, pre, (float*)d_out);
}

// Round 8
// 208.736 us; speedup vs baseline: 1.3167x; 1.3167x over previous
//
#include <hip/hip_runtime.h>
#include <hip/hip_bf16.h>

#define HID 128
#define LDK 136    // LDS row stride in shorts (272B): +4-bank skew/row, additive offsets
#define CPB 4      // cells per edge-block
#define CAP 16     // edges per cell (E/G)

// wt regions (bf16 elements): Wt[n][k] transposed weights
#define WT_M1L 0       // [128][128] mw1 rows 0..127   (prep_gemm)
#define WT_M2  16384   // [128][128]
#define WT_U1  32768   // [128][128]
#define WT_U2  49152   // [128][128]
#define WT_T   65536   // [128][128] Tt[n][a] = sum_f ew2[a][f]*mw1[128+f][n]
#define WT_TOTAL 81920

typedef __attribute__((ext_vector_type(8))) short bf16x8;
typedef __attribute__((ext_vector_type(4))) float f32x4;

#define MFMA(a, b, c) __builtin_amdgcn_mfma_f32_16x16x32_bf16(a, b, c, 0, 0, 0)

__device__ __forceinline__ float silu_f(float x) {
    return x * (1.0f / (1.0f + __expf(-x)));
}

__device__ __forceinline__ short f2b(float x) {
    __hip_bfloat16 h = __float2bfloat16(x);   // RNE
    return *(short*)&h;
}

__device__ __forceinline__ float b2f(unsigned short u) {
    union { unsigned u32; float f; } v;
    v.u32 = ((unsigned)u) << 16;
    return v.f;
}

// Fully-unrolled K=128 GEMM over 4 A-row-tiles x 32 weight cols.
template<int LDB, bool SWAP>
__device__ __forceinline__ void gemm128(f32x4 acc[4][2], const short* actb,
                                        const short* __restrict__ w0)
{
    const short* __restrict__ w1 = w0 + 16 * LDB;
    #pragma unroll
    for (int ks = 0; ks < 4; ++ks) {
        bf16x8 wa = *(const bf16x8*)(w0 + ks * 32);
        bf16x8 wb = *(const bf16x8*)(w1 + ks * 32);
        #pragma unroll
        for (int e4 = 0; e4 < 4; ++e4) {
            bf16x8 a = *(const bf16x8*)(actb + e4 * (16 * LDK) + ks * 32);
            if (SWAP) {
                acc[e4][0] = MFMA(wa, a, acc[e4][0]);
                acc[e4][1] = MFMA(wb, a, acc[e4][1]);
            } else {      // act as A: C rows = act rows, cols = weight cols
                acc[e4][0] = MFMA(a, wa, acc[e4][0]);
                acc[e4][1] = MFMA(a, wb, acc[e4][1]);
            }
        }
    }
}

// Small 16-row K=128 GEMM: A = 16 LDS rows, B = 32 weight cols.
__device__ __forceinline__ void gemm16(f32x4 a2[2], const short* ab,
                                       const short* __restrict__ w0)
{
    const short* __restrict__ w1 = w0 + 16 * 128;
    #pragma unroll
    for (int ks = 0; ks < 4; ++ks) {
        bf16x8 a  = *(const bf16x8*)(ab + ks * 32);
        bf16x8 b0 = *(const bf16x8*)(w0 + ks * 32);
        bf16x8 b1 = *(const bf16x8*)(w1 + ks * 32);
        a2[0] = MFMA(a, b0, a2[0]);
        a2[1] = MFMA(a, b1, a2[1]);
    }
}

// ---------------------------------------------------------------------------
// prep0: binning | weight transpose-cvt | T = ew2 @ mw1[128:] | bias2
// ---------------------------------------------------------------------------
extern "C" __global__ void __launch_bounds__(256)
prep0(const int* __restrict__ ei, int* __restrict__ cnt, int* __restrict__ bin, int E,
      const float* __restrict__ ew2, const float* __restrict__ eb2,
      const float* __restrict__ mw1, const float* __restrict__ mw2,
      const float* __restrict__ uw1, const float* __restrict__ uw2,
      short* __restrict__ wt, float* __restrict__ bias2)
{
    int nbin = (E + 255) / 256;
    int b = blockIdx.x;
    if (b < nbin) {                      // binning: store SOURCE NODE id
        int e = b * 256 + threadIdx.x;
        if (e < E) {
            int j = ei[E + e];
            int i = ei[e];
            int slot = atomicAdd(&cnt[j], 1);
            if (slot < CAP) bin[(size_t)j * CAP + slot] = i;
        }
        return;
    }
    b -= nbin;
    if (b < 256) {                       // transpose-convert M1L/M2/U1/U2
        int idx = b * 256 + threadIdx.x;
        int reg = idx >> 14, r = idx & 16383;
        int n = r >> 7, k = r & 127;
        const float* src = (reg == 0) ? mw1 : (reg == 1) ? mw2 : (reg == 2) ? uw1 : uw2;
        wt[idx] = f2b(src[k * HID + n]);
        return;
    }
    b -= 256;
    if (b < 64) {                        // Tt[n][a] = sum_f ew2[a][f]*mw1[128+f][n]
        int idx = b * 256 + threadIdx.x; // idx = n*128 + a
        int n = idx >> 7, a = idx & 127;
        const float* er = ew2 + (size_t)a * HID;
        float s = 0.0f;
        for (int f = 0; f < HID; ++f)
            s = fmaf(er[f], mw1[(size_t)(HID + f) * HID + n], s);
        wt[WT_T + idx] = f2b(s);
        return;
    }
    // bias2[n] = sum_f eb2[f]*mw1[128+f][n]
    int n = threadIdx.x;
    if (n < HID) {
        float s = 0.0f;
        for (int f = 0; f < HID; ++f)
            s = fmaf(eb2[f], mw1[(size_t)(HID + f) * HID + n], s);
        bias2[n] = s;
    }
}

// ---------------------------------------------------------------------------
// prep_gemm: pre[node] = emb[node] @ mw1[:128] + mb1 + bias2   (bf16 out)
// ---------------------------------------------------------------------------
extern "C" __global__ void __launch_bounds__(256, 4)
prep_gemm(const float* __restrict__ emb, const float* __restrict__ mb1,
          const float* __restrict__ bias2, const short* __restrict__ wt,
          unsigned short* __restrict__ pre)
{
    __shared__ short s_x[64 * LDK];
    const int t  = threadIdx.x;
    const int r0 = blockIdx.x * 64;

    {   // stage 64 fp32 rows -> bf16 LDS (padded rows)
        int row = t >> 2, part = t & 3;
        const float4* src = (const float4*)(emb + (size_t)(r0 + row) * HID + part * 32);
        short* dst = s_x + row * LDK + part * 32;
        #pragma unroll
        for (int c = 0; c < 4; ++c) {
            float4 v0 = src[c * 2], v1 = src[c * 2 + 1];
            short4 a4, b4;
            a4.x = f2b(v0.x); a4.y = f2b(v0.y); a4.z = f2b(v0.z); a4.w = f2b(v0.w);
            b4.x = f2b(v1.x); b4.y = f2b(v1.y); b4.z = f2b(v1.z); b4.w = f2b(v1.w);
            *(short4*)(dst + c * 8)     = a4;
            *(short4*)(dst + c * 8 + 4) = b4;
        }
    }
    __syncthreads();

    const int lane = t & 63, q = lane & 15, h = lane >> 4, nb = (t >> 6) * 32;
    f32x4 acc[4][2];
    #pragma unroll
    for (int m = 0; m < 4; ++m) { acc[m][0] = (f32x4)(0.0f); acc[m][1] = (f32x4)(0.0f); }
    gemm128<128, false>(acc, s_x + q * LDK + h * 8, wt + WT_M1L + (nb + q) * 128 + h * 8);

    #pragma unroll
    for (int nf = 0; nf < 2; ++nf) {
        int n = nb + nf * 16 + q;
        float bb = mb1[n] + bias2[n];
        #pragma unroll
        for (int m = 0; m < 4; ++m)
            #pragma unroll
            for (int r = 0; r < 4; ++r)
                pre[(size_t)(r0 + m * 16 + h * 4 + r) * HID + n] =
                    (unsigned short)f2b(acc[m][nf][r] + bb);
    }
}

// ---------------------------------------------------------------------------
// edge kernel: 4 cells x 16 edges. h1 direct -> ONE fused T-GEMM -> silu+pre
// in registers -> per-cell sum (in-register + 2 shfl) -> 3 tiny 16-row GEMMs
// (mw2 with deferred 1/c, uw1+silu, uw2) -> out. h2 never touches LDS.
// ---------------------------------------------------------------------------
extern "C" __global__ void __launch_bounds__(256, 4)
edge_kernel(const float* __restrict__ npos,
            const float* __restrict__ gpos,
            const float* __restrict__ ew1, const float* __restrict__ eb1,
            const float* __restrict__ mb2,
            const float* __restrict__ ub1, const float* __restrict__ ub2,
            const short* __restrict__ wt,
            const int* __restrict__ cnt,
            const int* __restrict__ bin,
            const unsigned short* __restrict__ pre,
            float* __restrict__ out)
{
    __shared__ short s_h1[64 * LDK];   // h1 acts
    __shared__ short s_m1[16 * LDK];   // cell sums (rows 0..3 real)
    __shared__ short s_m2[16 * LDK];   // mean@mw2+mb2
    __shared__ short s_u [16 * LDK];   // u1

    const int t  = threadIdx.x;
    const int c0 = blockIdx.x * CPB;
    const int lane = t & 63, q = lane & 15, h = lane >> 4, nb = (t >> 6) * 32;

    // ---- ids for L1 rows (e4*16+q)
    int idL[4];
    #pragma unroll
    for (int e4 = 0; e4 < 4; ++e4)
        idL[e4] = bin[c0 * CAP + e4 * 16 + q];

    float np0[4], np1[4], np2[4];
    #pragma unroll
    for (int e4 = 0; e4 < 4; ++e4) {
        const float* p = npos + (size_t)idL[e4] * 3;
        np0[e4] = p[0]; np1[e4] = p[1]; np2[e4] = p[2];
    }

    // wave-uniform: grid positions + counts
    float g0[4], g1[4], g2[4], inv[4];
    #pragma unroll
    for (int m = 0; m < 4; ++m) {
        const float* gp = gpos + (size_t)(c0 + m) * 3;
        g0[m] = gp[0]; g1[m] = gp[1]; g2[m] = gp[2];
        int c = cnt[c0 + m];
        inv[m] = 1.0f / (float)(c > 0 ? c : 1);
    }

    const int f00 = nb + h * 4;
    short* wx = s_h1 + q * LDK + nb + h * 4;   // L1 write base

    // ---- L1 (direct fp32): h1 = silu(np.ew1[0:3] + gp.ew1[3:6] + eb1) -> s_h1
    #pragma unroll
    for (int nf = 0; nf < 2; ++nf) {
        int f0 = f00 + nf * 16;
        float4 wn0 = *(const float4*)(ew1 + 0 * HID + f0);
        float4 wn1 = *(const float4*)(ew1 + 1 * HID + f0);
        float4 wn2 = *(const float4*)(ew1 + 2 * HID + f0);
        float4 wg0 = *(const float4*)(ew1 + 3 * HID + f0);
        float4 wg1 = *(const float4*)(ew1 + 4 * HID + f0);
        float4 wg2 = *(const float4*)(ew1 + 5 * HID + f0);
        float4 bb  = *(const float4*)(eb1 + f0);
        #pragma unroll
        for (int e4 = 0; e4 < 4; ++e4) {
            float bx = bb.x + g0[e4] * wg0.x + g1[e4] * wg1.x + g2[e4] * wg2.x;
            float by = bb.y + g0[e4] * wg0.y + g1[e4] * wg1.y + g2[e4] * wg2.y;
            float bz = bb.z + g0[e4] * wg0.z + g1[e4] * wg1.z + g2[e4] * wg2.z;
            float bw = bb.w + g0[e4] * wg0.w + g1[e4] * wg1.w + g2[e4] * wg2.w;
            float z0 = silu_f(bx + np0[e4] * wn0.x + np1[e4] * wn1.x + np2[e4] * wn2.x);
            float z1 = silu_f(by + np0[e4] * wn0.y + np1[e4] * wn1.y + np2[e4] * wn2.y);
            float z2 = silu_f(bz + np0[e4] * wn0.z + np1[e4] * wn1.z + np2[e4] * wn2.z);
            float z3 = silu_f(bw + np0[e4] * wn0.w + np1[e4] * wn1.w + np2[e4] * wn2.w);
            short4 s4;
            s4.x = f2b(z0); s4.y = f2b(z1); s4.z = f2b(z2); s4.w = f2b(z3);
            *(short4*)(wx + e4 * (16 * LDK) + nf * 16) = s4;
        }
    }

    // ---- T14: pre[] gather for T-epi rows (m*16+h*4+r), cols nb+q / nb+16+q.
    // Issued before B1; consumed after the T-GEMM (~500cy later).
    unsigned short pA[4][4], pB[4][4];
    #pragma unroll
    for (int m = 0; m < 4; ++m) {
        #pragma unroll
        for (int r = 0; r < 4; ++r) {
            int id = bin[c0 * CAP + m * 16 + h * 4 + r];
            const unsigned short* pr = pre + (size_t)id * HID;
            pA[m][r] = pr[nb + q];
            pB[m][r] = pr[nb + 16 + q];
        }
    }
    __syncthreads();                                   // B1: h1 visible

    // ---- T-GEMM: h2in = h1 @ T  (actA: C rows = edges m*16+h*4+r, cols nb(+16)+q)
    f32x4 acc[4][2];
    #pragma unroll
    for (int m = 0; m < 4; ++m) { acc[m][0] = (f32x4)(0.0f); acc[m][1] = (f32x4)(0.0f); }
    gemm128<128, false>(acc, s_h1 + q * LDK + h * 8, wt + WT_T + (nb + q) * 128 + h * 8);

    // ---- silu(h2in + pre) in registers; per-cell sum (r-sum + h-shfl); -> s_m1
    #pragma unroll
    for (int m = 0; m < 4; ++m) {
        #pragma unroll
        for (int nf = 0; nf < 2; ++nf) {
            f32x4 v = acc[m][nf];
            float s = silu_f(v[0] + b2f(nf ? pB[m][0] : pA[m][0]));
            s += silu_f(v[1] + b2f(nf ? pB[m][1] : pA[m][1]));
            s += silu_f(v[2] + b2f(nf ? pB[m][2] : pA[m][2]));
            s += silu_f(v[3] + b2f(nf ? pB[m][3] : pA[m][3]));
            s += __shfl_xor(s, 16);
            s += __shfl_xor(s, 32);
            if (h == 0)
                s_m1[m * LDK + nb + nf * 16 + q] = f2b(s);   // SUM (1/c deferred)
        }
    }
    __syncthreads();                                   // B2: sums visible

    // ---- G1: mean = (S @ mw2)*inv + mb2 -> s_m2 (rows 0..3; exact fp32 inv)
    f32x4 a2[2];
    a2[0] = (f32x4)(0.0f); a2[1] = (f32x4)(0.0f);
    gemm16(a2, s_m1 + q * LDK + h * 8, wt + WT_M2 + (nb + q) * 128 + h * 8);
    if (h == 0) {
        #pragma unroll
        for (int nf = 0; nf < 2; ++nf) {
            int n = nb + nf * 16 + q;
            float bb = mb2[n];
            #pragma unroll
            for (int r = 0; r < 4; ++r)
                s_m2[r * LDK + n] = f2b(a2[nf][r] * inv[r] + bb);
        }
    }
    __syncthreads();                                   // B3

    // ---- G2: u1 = silu(mean @ uw1 + ub1) -> s_u (rows 0..3)
    a2[0] = (f32x4)(0.0f); a2[1] = (f32x4)(0.0f);
    gemm16(a2, s_m2 + q * LDK + h * 8, wt + WT_U1 + (nb + q) * 128 + h * 8);
    if (h == 0) {
        #pragma unroll
        for (int nf = 0; nf < 2; ++nf) {
            int n = nb + nf * 16 + q;
            float bb = ub1[n];
            #pragma unroll
            for (int r = 0; r < 4; ++r)
                s_u[r * LDK + n] = f2b(silu_f(a2[nf][r] + bb));
        }
    }
    __syncthreads();                                   // B4

    // ---- G3: out = u1 @ uw2 + ub2  (C rows 0..3 = cells)
    a2[0] = (f32x4)(0.0f); a2[1] = (f32x4)(0.0f);
    gemm16(a2, s_u + q * LDK + h * 8, wt + WT_U2 + (nb + q) * 128 + h * 8);
    if (h == 0) {
        #pragma unroll
        for (int nf = 0; nf < 2; ++nf) {
            int n = nb + nf * 16 + q;
            float bb = ub2[n];
            #pragma unroll
            for (int r = 0; r < 4; ++r)
                out[(size_t)(c0 + r) * HID + n] = a2[nf][r] + bb;
        }
    }
}

// ---------------------------------------------------------------------------
extern "C" void kernel_launch(void* const* d_in, const int* in_sizes, int n_in,
                              void* d_out, int out_size, void* d_ws, size_t ws_size,
                              hipStream_t stream)
{
    const float* emb  = (const float*)d_in[0];
    const float* npos = (const float*)d_in[1];
    const float* gpos = (const float*)d_in[2];
    const int*   ei   = (const int*)d_in[3];
    const float* ew1  = (const float*)d_in[4];
    const float* eb1  = (const float*)d_in[5];
    const float* ew2  = (const float*)d_in[6];
    const float* eb2  = (const float*)d_in[7];
    const float* mw1  = (const float*)d_in[8];
    const float* mb1  = (const float*)d_in[9];
    const float* mw2  = (const float*)d_in[10];
    const float* mb2  = (const float*)d_in[11];
    const float* uw1  = (const float*)d_in[12];
    const float* ub1  = (const float*)d_in[13];
    const float* uw2  = (const float*)d_in[14];
    const float* ub2  = (const float*)d_in[15];

    const int E  = in_sizes[3] / 2;
    const int G  = in_sizes[2] / 3;
    const int NN = in_sizes[0] / HID;

    // ws: pre bf16[NN*HID] | cnt int[G] | bin int[G*CAP] | wt bf16[WT_TOTAL] | bias2 f32[128]
    unsigned short* pre = (unsigned short*)d_ws;
    char* p = (char*)d_ws + (size_t)NN * HID * 2;
    int*   cnt = (int*)p;                 p += (size_t)G * 4;
    int*   bin = (int*)p;                 p += (size_t)G * CAP * 4;
    short* wt  = (short*)p;               p += (size_t)WT_TOTAL * 2;
    float* bias2 = (float*)p;

    hipMemsetAsync(cnt, 0, (size_t)G * (4 + CAP * 4), stream);   // cnt + bin

    int nbin = (E + 255) / 256;
    prep0<<<nbin + 256 + 64 + 1, 256, 0, stream>>>(ei, cnt, bin, E,
                                                   ew2, eb2, mw1, mw2, uw1, uw2,
                                                   wt, bias2);
    prep_gemm<<<NN / 64, 256, 0, stream>>>(emb, mb1, bias2, wt, pre);
    edge_kernel<<<G / CPB, 256, 0, stream>>>(npos, gpos, ew1, eb1, mb2, ub1, ub2,
                                             wt, cnt, bin, pre, (float*)d_out);
}